// Round 2
// baseline (318.355 us; speedup 1.0000x reference)
//
#include <hip/hip_runtime.h>
#include <hip/hip_bf16.h>

#define TOKENS 4096
#define IN_F   4096
#define OUT_F  4096

typedef __bf16 bf16x8 __attribute__((ext_vector_type(8)));
typedef float  f32x4  __attribute__((ext_vector_type(4)));
typedef unsigned int u32;

__device__ __forceinline__ void gld_lds16(const void* g, void* l) {
    __builtin_amdgcn_global_load_lds(
        (const __attribute__((address_space(1))) u32*)g,
        (__attribute__((address_space(3))) u32*)l,
        16, 0, 0);
}

// ---------------------------------------------------------------------------
// 1) Dequantize packed int4 -> bf16 W[n][k] row-major (4096 x 4096).
// ---------------------------------------------------------------------------
__global__ __launch_bounds__(256) void dequant_kernel(
        const u32* __restrict__ qweight, const u32* __restrict__ qzeros,
        const float* __restrict__ scales, __bf16* __restrict__ W) {
    int idx = blockIdx.x * 256 + threadIdx.x;   // 0 .. 4096*512-1
    int n = idx >> 9;                           // out row
    int p = idx & 511;                          // packed col
    int g = p >> 4;                             // group id (0..31)
    u32 qw = qweight[idx];
    u32 qz = qzeros[(n << 2) + (g >> 3)];
    float z = (float)((qz >> ((g & 7) * 4)) & 15);
    float s = scales[(n << 5) + g];
    bf16x8 h;
#pragma unroll
    for (int j = 0; j < 8; ++j) {
        float w = ((float)((qw >> (4 * j)) & 15) - z) * s;
        h[j] = (__bf16)w;
    }
    *((bf16x8*)W + idx) = h;
}

// ---------------------------------------------------------------------------
// 2) Convert x fp32 -> bf16 (row-major A[m][k]). 8 elements/thread.
// ---------------------------------------------------------------------------
__global__ __launch_bounds__(256) void cvt_kernel(
        const float* __restrict__ x, __bf16* __restrict__ A) {
    int idx = blockIdx.x * 256 + threadIdx.x;   // 0 .. 4096*4096/8-1
    const f32x4* xp = (const f32x4*)x + (size_t)idx * 2;
    f32x4 a = xp[0], b = xp[1];
    bf16x8 h;
#pragma unroll
    for (int j = 0; j < 4; ++j) { h[j] = (__bf16)a[j]; h[4 + j] = (__bf16)b[j]; }
    *((bf16x8*)A + idx) = h;
}

// ---------------------------------------------------------------------------
// 3) GEMM: C[m][n] = sum_k A[m][k]*B[n][k] + bias[n]   (B^T-input form)
//    m97 structure: 128x128 tile, BK=32, 256 threads (4 waves, 2x2 of 64x64),
//    mfma_f32_16x16x32_bf16 4x4 per wave, global_load_lds width=16 staging.
//
//    LDS swizzle: tile row r occupies bytes [r*64, r*64+64); its four 16B
//    chunks are stored PERMUTED: slot s holds global chunk (s ^ ((r>>1)&3)).
//    This makes the fragment ds_read_b128 (16 lanes, 64B row stride, fixed
//    chunk) hit all 8 bank-groups per 8-lane phase -> conflict-free.
//    Staging side: thread with chunk-slot q fetches global chunk
//    (q&3)^((row>>1)&3); LDS dest stays contiguous (wave-uniform base +
//    lane*16 as global_load_lds requires). Same-row lanes are merely
//    permuted within the same 64B -> coalescing unchanged.
// ---------------------------------------------------------------------------
__global__ __launch_bounds__(256) void gemm_bt(
        const __bf16* __restrict__ A, const __bf16* __restrict__ B,
        const float* __restrict__ bias, float* __restrict__ C) {
    __shared__ __align__(16) __bf16 lsA[128 * 32];
    __shared__ __align__(16) __bf16 lsB[128 * 32];

    const int t    = threadIdx.x;
    const int bm   = blockIdx.y, bn = blockIdx.x;
    const int lane = t & 63, wave = t >> 6;
    const int wm   = (wave >> 1) * 64;     // wave row offset in tile
    const int wn   = (wave & 1) * 64;      // wave col offset in tile
    const int lr   = lane & 15;            // row-in-16 for A/B fragments
    const int quad = lane >> 4;            // k-chunk index (8 elems each)

    const __bf16* Abase = A + (size_t)bm * 128 * IN_F;
    const __bf16* Bbase = B + (size_t)bn * 128 * IN_F;

    // staging: thread t handles chunk-slots t and t+256 (slot q -> row q>>2,
    // slot-in-row q&3). Global chunk fetched = slot ^ ((row>>1)&3).
    const int q0 = t, q1 = t + 256;
    const int ar0 = q0 >> 2, ac0 = (((q0 & 3) ^ ((ar0 >> 1) & 3))) * 8;
    const int ar1 = q1 >> 2, ac1 = (((q1 & 3) ^ ((ar1 >> 1) & 3))) * 8;

    f32x4 acc[4][4] = {};

    for (int k0 = 0; k0 < IN_F; k0 += 32) {
        gld_lds16(Abase + (size_t)ar0 * IN_F + k0 + ac0, (char*)lsA + q0 * 16);
        gld_lds16(Abase + (size_t)ar1 * IN_F + k0 + ac1, (char*)lsA + q1 * 16);
        gld_lds16(Bbase + (size_t)ar0 * IN_F + k0 + ac0, (char*)lsB + q0 * 16);
        gld_lds16(Bbase + (size_t)ar1 * IN_F + k0 + ac1, (char*)lsB + q1 * 16);
        __syncthreads();

        bf16x8 af[4], bf[4];
#pragma unroll
        for (int i = 0; i < 4; ++i) {
            const int Ra = wm + i * 16 + lr;
            const int Rb = wn + i * 16 + lr;
            af[i] = *(const bf16x8*)(lsA + Ra * 32 + ((quad ^ ((Ra >> 1) & 3)) * 8));
            bf[i] = *(const bf16x8*)(lsB + Rb * 32 + ((quad ^ ((Rb >> 1) & 3)) * 8));
        }
#pragma unroll
        for (int i = 0; i < 4; ++i)
#pragma unroll
            for (int j = 0; j < 4; ++j)
                acc[i][j] = __builtin_amdgcn_mfma_f32_16x16x32_bf16(
                    af[i], bf[j], acc[i][j], 0, 0, 0);
        __syncthreads();
    }

    // epilogue: C/D layout col = lane&15, row = (lane>>4)*4 + reg
    const int row0 = bm * 128 + wm + quad * 4;
    const int col0 = bn * 128 + wn + lr;
#pragma unroll
    for (int j = 0; j < 4; ++j) {
        const int col = col0 + j * 16;
        const float bv = bias[col];
#pragma unroll
        for (int i = 0; i < 4; ++i) {
            const int row = row0 + i * 16;
#pragma unroll
            for (int r = 0; r < 4; ++r)
                C[(size_t)(row + r) * OUT_F + col] = acc[i][j][r] + bv;
        }
    }
}

extern "C" void kernel_launch(void* const* d_in, const int* in_sizes, int n_in,
                              void* d_out, int out_size, void* d_ws, size_t ws_size,
                              hipStream_t stream) {
    (void)in_sizes; (void)n_in; (void)out_size; (void)ws_size;
    const float* x       = (const float*)d_in[0];
    const u32*   qweight = (const u32*)d_in[1];
    const u32*   qzeros  = (const u32*)d_in[2];
    const float* scales  = (const float*)d_in[3];
    const float* bias    = (const float*)d_in[4];
    float* out = (float*)d_out;

    __bf16* W   = (__bf16*)d_ws;                                     // 32 MB
    __bf16* Abf = (__bf16*)((char*)d_ws + (size_t)OUT_F * IN_F * 2); // 32 MB

    dequant_kernel<<<dim3(OUT_F * (IN_F / 8) / 256), dim3(256), 0, stream>>>(
        qweight, qzeros, scales, W);
    cvt_kernel<<<dim3(TOKENS * IN_F / 8 / 256), dim3(256), 0, stream>>>(x, Abf);
    gemm_bt<<<dim3(OUT_F / 128, TOKENS / 128), dim3(256), 0, stream>>>(
        Abf, W, bias, out);
}

// Round 3
// 307.893 us; speedup vs baseline: 1.0340x; 1.0340x over previous
//
#include <hip/hip_runtime.h>
#include <hip/hip_bf16.h>

#define TOKENS 4096
#define IN_F   4096
#define OUT_F  4096

typedef __bf16 bf16x8 __attribute__((ext_vector_type(8)));
typedef float  f32x4  __attribute__((ext_vector_type(4)));
typedef unsigned int u32;
typedef u32 u32x4 __attribute__((ext_vector_type(4)));

#define DEQ_BLOCKS 2048   // 4096 rows * 128 thread-chunks / 256
#define CVT_BLOCKS 4096   // 4096*4096 /16 /256

__device__ __forceinline__ void gld_lds16(const void* g, void* l) {
    __builtin_amdgcn_global_load_lds(
        (const __attribute__((address_space(1))) u32*)g,
        (__attribute__((address_space(3))) u32*)l,
        16, 0, 0);
}

// ---------------------------------------------------------------------------
// Fused prep: blockIdx < DEQ_BLOCKS  -> dequant int4 W (16B qweight loads,
//             32 weights/thread, 64B contiguous store)
//             else                   -> x fp32->bf16 (16 elems/thread)
// ---------------------------------------------------------------------------
__global__ __launch_bounds__(256) void prep_kernel(
        const u32* __restrict__ qweight, const u32* __restrict__ qzeros,
        const float* __restrict__ scales, const float* __restrict__ x,
        __bf16* __restrict__ W, __bf16* __restrict__ A) {
    const int tid = threadIdx.x;
    if (blockIdx.x < DEQ_BLOCKS) {
        int idx4 = blockIdx.x * 256 + tid;      // 0 .. 524287
        int n  = idx4 >> 7;                     // out row (128 chunks/row)
        int p4 = (idx4 & 127) << 2;             // first packed col (0..508)
        int g  = p4 >> 4;                       // group id (constant over 4)
        u32 qz = qzeros[(n << 2) + (g >> 3)];
        float z = (float)((qz >> ((g & 7) * 4)) & 15);
        float s = scales[(n << 5) + g];
        u32x4 qw = *(const u32x4*)(qweight + (size_t)n * 512 + p4);
        __bf16* dst = W + (size_t)n * IN_F + p4 * 8;
#pragma unroll
        for (int c = 0; c < 4; ++c) {
            bf16x8 h;
#pragma unroll
            for (int j = 0; j < 8; ++j) {
                float w = ((float)((qw[c] >> (4 * j)) & 15) - z) * s;
                h[j] = (__bf16)w;
            }
            *(bf16x8*)(dst + c * 8) = h;
        }
    } else {
        int idx = (blockIdx.x - DEQ_BLOCKS) * 256 + tid;   // 0 .. 1048575
        const f32x4* xp = (const f32x4*)x + (size_t)idx * 4;
        f32x4 v0 = xp[0], v1 = xp[1], v2 = xp[2], v3 = xp[3];
        bf16x8 h0, h1;
#pragma unroll
        for (int j = 0; j < 4; ++j) {
            h0[j] = (__bf16)v0[j]; h0[4 + j] = (__bf16)v1[j];
            h1[j] = (__bf16)v2[j]; h1[4 + j] = (__bf16)v3[j];
        }
        bf16x8* ap = (bf16x8*)A + (size_t)idx * 2;
        ap[0] = h0; ap[1] = h1;
    }
}

// ---------------------------------------------------------------------------
// GEMM: C[m][n] = sum_k A[m][k]*B[n][k] + bias[n]   (B^T-input form)
//    128x128 tile, BK=32, 256 threads (4 waves, 2x2 of 64x64),
//    mfma_f32_16x16x32_bf16 4x4 per wave, global_load_lds width=16 staging.
//    XOR chunk swizzle -> SQ_LDS_BANK_CONFLICT == 0 (verified R2).
// ---------------------------------------------------------------------------
__global__ __launch_bounds__(256) void gemm_bt(
        const __bf16* __restrict__ A, const __bf16* __restrict__ B,
        const float* __restrict__ bias, float* __restrict__ C) {
    __shared__ __align__(16) __bf16 lsA[128 * 32];
    __shared__ __align__(16) __bf16 lsB[128 * 32];

    const int t    = threadIdx.x;
    const int bm   = blockIdx.y, bn = blockIdx.x;
    const int lane = t & 63, wave = t >> 6;
    const int wm   = (wave >> 1) * 64;
    const int wn   = (wave & 1) * 64;
    const int lr   = lane & 15;
    const int quad = lane >> 4;

    const __bf16* Abase = A + (size_t)bm * 128 * IN_F;
    const __bf16* Bbase = B + (size_t)bn * 128 * IN_F;

    const int q0 = t, q1 = t + 256;
    const int ar0 = q0 >> 2, ac0 = (((q0 & 3) ^ ((ar0 >> 1) & 3))) * 8;
    const int ar1 = q1 >> 2, ac1 = (((q1 & 3) ^ ((ar1 >> 1) & 3))) * 8;

    f32x4 acc[4][4] = {};

    for (int k0 = 0; k0 < IN_F; k0 += 32) {
        gld_lds16(Abase + (size_t)ar0 * IN_F + k0 + ac0, (char*)lsA + q0 * 16);
        gld_lds16(Abase + (size_t)ar1 * IN_F + k0 + ac1, (char*)lsA + q1 * 16);
        gld_lds16(Bbase + (size_t)ar0 * IN_F + k0 + ac0, (char*)lsB + q0 * 16);
        gld_lds16(Bbase + (size_t)ar1 * IN_F + k0 + ac1, (char*)lsB + q1 * 16);
        __syncthreads();

        bf16x8 af[4], bf[4];
#pragma unroll
        for (int i = 0; i < 4; ++i) {
            const int Ra = wm + i * 16 + lr;
            const int Rb = wn + i * 16 + lr;
            af[i] = *(const bf16x8*)(lsA + Ra * 32 + ((quad ^ ((Ra >> 1) & 3)) * 8));
            bf[i] = *(const bf16x8*)(lsB + Rb * 32 + ((quad ^ ((Rb >> 1) & 3)) * 8));
        }
#pragma unroll
        for (int i = 0; i < 4; ++i)
#pragma unroll
            for (int j = 0; j < 4; ++j)
                acc[i][j] = __builtin_amdgcn_mfma_f32_16x16x32_bf16(
                    af[i], bf[j], acc[i][j], 0, 0, 0);
        __syncthreads();
    }

    const int row0 = bm * 128 + wm + quad * 4;
    const int col0 = bn * 128 + wn + lr;
#pragma unroll
    for (int j = 0; j < 4; ++j) {
        const int col = col0 + j * 16;
        const float bv = bias[col];
#pragma unroll
        for (int i = 0; i < 4; ++i) {
            const int row = row0 + i * 16;
#pragma unroll
            for (int r = 0; r < 4; ++r)
                C[(size_t)(row + r) * OUT_F + col] = acc[i][j][r] + bv;
        }
    }
}

extern "C" void kernel_launch(void* const* d_in, const int* in_sizes, int n_in,
                              void* d_out, int out_size, void* d_ws, size_t ws_size,
                              hipStream_t stream) {
    (void)in_sizes; (void)n_in; (void)out_size; (void)ws_size;
    const float* x       = (const float*)d_in[0];
    const u32*   qweight = (const u32*)d_in[1];
    const u32*   qzeros  = (const u32*)d_in[2];
    const float* scales  = (const float*)d_in[3];
    const float* bias    = (const float*)d_in[4];
    float* out = (float*)d_out;

    __bf16* W   = (__bf16*)d_ws;                                     // 32 MB
    __bf16* Abf = (__bf16*)((char*)d_ws + (size_t)OUT_F * IN_F * 2); // 32 MB

    prep_kernel<<<dim3(DEQ_BLOCKS + CVT_BLOCKS), dim3(256), 0, stream>>>(
        qweight, qzeros, scales, x, W, Abf);
    gemm_bt<<<dim3(OUT_F / 128, TOKENS / 128), dim3(256), 0, stream>>>(
        Abf, W, bias, out);
}

// Round 4
// 292.552 us; speedup vs baseline: 1.0882x; 1.0524x over previous
//
#include <hip/hip_runtime.h>
#include <hip/hip_bf16.h>

#define TOKENS 4096
#define IN_F   4096
#define OUT_F  4096

typedef __bf16 bf16x8 __attribute__((ext_vector_type(8)));
typedef float  f32x4  __attribute__((ext_vector_type(4)));
typedef unsigned int u32;
typedef u32 u32x4 __attribute__((ext_vector_type(4)));

#define DEQ_BLOCKS 2048   // 4096 rows * 128 thread-chunks / 256
#define CVT_BLOCKS 4096   // 4096*4096 /16 /256

__device__ __forceinline__ void gld_lds16(const void* g, void* l) {
    __builtin_amdgcn_global_load_lds(
        (const __attribute__((address_space(1))) u32*)g,
        (__attribute__((address_space(3))) u32*)l,
        16, 0, 0);
}

// ---------------------------------------------------------------------------
// Fused prep: blockIdx < DEQ_BLOCKS  -> dequant int4 W (16B qweight loads,
//             32 weights/thread, 64B contiguous store)
//             else                   -> x fp32->bf16 (16 elems/thread)
// ---------------------------------------------------------------------------
__global__ __launch_bounds__(256) void prep_kernel(
        const u32* __restrict__ qweight, const u32* __restrict__ qzeros,
        const float* __restrict__ scales, const float* __restrict__ x,
        __bf16* __restrict__ W, __bf16* __restrict__ A) {
    const int tid = threadIdx.x;
    if (blockIdx.x < DEQ_BLOCKS) {
        int idx4 = blockIdx.x * 256 + tid;      // 0 .. 524287
        int n  = idx4 >> 7;                     // out row (128 chunks/row)
        int p4 = (idx4 & 127) << 2;             // first packed col (0..508)
        int g  = p4 >> 4;                       // group id (constant over 4)
        u32 qz = qzeros[(n << 2) + (g >> 3)];
        float z = (float)((qz >> ((g & 7) * 4)) & 15);
        float s = scales[(n << 5) + g];
        u32x4 qw = *(const u32x4*)(qweight + (size_t)n * 512 + p4);
        __bf16* dst = W + (size_t)n * IN_F + p4 * 8;
#pragma unroll
        for (int c = 0; c < 4; ++c) {
            bf16x8 h;
#pragma unroll
            for (int j = 0; j < 8; ++j) {
                float w = ((float)((qw[c] >> (4 * j)) & 15) - z) * s;
                h[j] = (__bf16)w;
            }
            *(bf16x8*)(dst + c * 8) = h;
        }
    } else {
        int idx = (blockIdx.x - DEQ_BLOCKS) * 256 + tid;   // 0 .. 1048575
        const f32x4* xp = (const f32x4*)x + (size_t)idx * 4;
        f32x4 v0 = xp[0], v1 = xp[1], v2 = xp[2], v3 = xp[3];
        bf16x8 h0, h1;
#pragma unroll
        for (int j = 0; j < 4; ++j) {
            h0[j] = (__bf16)v0[j]; h0[4 + j] = (__bf16)v1[j];
            h1[j] = (__bf16)v2[j]; h1[4 + j] = (__bf16)v3[j];
        }
        bf16x8* ap = (bf16x8*)A + (size_t)idx * 2;
        ap[0] = h0; ap[1] = h1;
    }
}

// ---------------------------------------------------------------------------
// GEMM: C[m][n] = sum_k A[m][k]*B[n][k] + bias[n]   (B^T-input form)
//    128x128 tile, BK=32, 256 threads (4 waves, 2x2 of 64x64),
//    mfma_f32_16x16x32_bf16 4x4 per wave, global_load_lds width=16 staging.
//    XOR chunk swizzle -> SQ_LDS_BANK_CONFLICT == 0 (verified R2).
//    __launch_bounds__(256,4): cap regs at 128/wave so 4 blocks/CU fit —
//    grid is exactly 4 blocks/CU of work; at 3 blocks/CU the last batch
//    runs 1 block/CU (measured 23% occupancy = (12+4)/2 waves tail).
// ---------------------------------------------------------------------------
__global__ __launch_bounds__(256, 4) void gemm_bt(
        const __bf16* __restrict__ A, const __bf16* __restrict__ B,
        const float* __restrict__ bias, float* __restrict__ C) {
    __shared__ __align__(16) __bf16 lsA[128 * 32];
    __shared__ __align__(16) __bf16 lsB[128 * 32];

    const int t    = threadIdx.x;
    const int bm   = blockIdx.y, bn = blockIdx.x;
    const int lane = t & 63, wave = t >> 6;
    const int wm   = (wave >> 1) * 64;
    const int wn   = (wave & 1) * 64;
    const int lr   = lane & 15;
    const int quad = lane >> 4;

    const __bf16* Abase = A + (size_t)bm * 128 * IN_F;
    const __bf16* Bbase = B + (size_t)bn * 128 * IN_F;

    const int q0 = t, q1 = t + 256;
    const int ar0 = q0 >> 2, ac0 = (((q0 & 3) ^ ((ar0 >> 1) & 3))) * 8;
    const int ar1 = q1 >> 2, ac1 = (((q1 & 3) ^ ((ar1 >> 1) & 3))) * 8;

    f32x4 acc[4][4] = {};

    for (int k0 = 0; k0 < IN_F; k0 += 32) {
        gld_lds16(Abase + (size_t)ar0 * IN_F + k0 + ac0, (char*)lsA + q0 * 16);
        gld_lds16(Abase + (size_t)ar1 * IN_F + k0 + ac1, (char*)lsA + q1 * 16);
        gld_lds16(Bbase + (size_t)ar0 * IN_F + k0 + ac0, (char*)lsB + q0 * 16);
        gld_lds16(Bbase + (size_t)ar1 * IN_F + k0 + ac1, (char*)lsB + q1 * 16);
        __syncthreads();

        bf16x8 af[4], bf[4];
#pragma unroll
        for (int i = 0; i < 4; ++i) {
            const int Ra = wm + i * 16 + lr;
            const int Rb = wn + i * 16 + lr;
            af[i] = *(const bf16x8*)(lsA + Ra * 32 + ((quad ^ ((Ra >> 1) & 3)) * 8));
            bf[i] = *(const bf16x8*)(lsB + Rb * 32 + ((quad ^ ((Rb >> 1) & 3)) * 8));
        }
#pragma unroll
        for (int i = 0; i < 4; ++i)
#pragma unroll
            for (int j = 0; j < 4; ++j)
                acc[i][j] = __builtin_amdgcn_mfma_f32_16x16x32_bf16(
                    af[i], bf[j], acc[i][j], 0, 0, 0);
        __syncthreads();
    }

    const int row0 = bm * 128 + wm + quad * 4;
    const int col0 = bn * 128 + wn + lr;
#pragma unroll
    for (int j = 0; j < 4; ++j) {
        const int col = col0 + j * 16;
        const float bv = bias[col];
#pragma unroll
        for (int i = 0; i < 4; ++i) {
            const int row = row0 + i * 16;
#pragma unroll
            for (int r = 0; r < 4; ++r)
                C[(size_t)(row + r) * OUT_F + col] = acc[i][j][r] + bv;
        }
    }
}

extern "C" void kernel_launch(void* const* d_in, const int* in_sizes, int n_in,
                              void* d_out, int out_size, void* d_ws, size_t ws_size,
                              hipStream_t stream) {
    (void)in_sizes; (void)n_in; (void)out_size; (void)ws_size;
    const float* x       = (const float*)d_in[0];
    const u32*   qweight = (const u32*)d_in[1];
    const u32*   qzeros  = (const u32*)d_in[2];
    const float* scales  = (const float*)d_in[3];
    const float* bias    = (const float*)d_in[4];
    float* out = (float*)d_out;

    __bf16* W   = (__bf16*)d_ws;                                     // 32 MB
    __bf16* Abf = (__bf16*)((char*)d_ws + (size_t)OUT_F * IN_F * 2); // 32 MB

    prep_kernel<<<dim3(DEQ_BLOCKS + CVT_BLOCKS), dim3(256), 0, stream>>>(
        qweight, qzeros, scales, x, W, Abf);
    gemm_bt<<<dim3(OUT_F / 128, TOKENS / 128), dim3(256), 0, stream>>>(
        Abf, W, bias, out);
}

// Round 5
// 269.005 us; speedup vs baseline: 1.1835x; 1.0875x over previous
//
#include <hip/hip_runtime.h>
#include <hip/hip_bf16.h>

#define TOKENS 4096
#define IN_F   4096
#define OUT_F  4096

typedef __bf16 bf16x8 __attribute__((ext_vector_type(8)));
typedef float  f32x4  __attribute__((ext_vector_type(4)));
typedef unsigned int u32;
typedef u32 u32x4 __attribute__((ext_vector_type(4)));

#define DEQ_BLOCKS 2048   // 4096 rows * 128 thread-chunks / 256
#define CVT_BLOCKS 4096   // 4096*4096 /16 /256

__device__ __forceinline__ void gld_lds16(const void* g, void* l) {
    __builtin_amdgcn_global_load_lds(
        (const __attribute__((address_space(1))) u32*)g,
        (__attribute__((address_space(3))) u32*)l,
        16, 0, 0);
}

// ---------------------------------------------------------------------------
// Fused prep: blockIdx < DEQ_BLOCKS  -> dequant int4 W (16B qweight loads,
//             32 weights/thread, 64B contiguous store)
//             else                   -> x fp32->bf16 (16 elems/thread)
// ---------------------------------------------------------------------------
__global__ __launch_bounds__(256) void prep_kernel(
        const u32* __restrict__ qweight, const u32* __restrict__ qzeros,
        const float* __restrict__ scales, const float* __restrict__ x,
        __bf16* __restrict__ W, __bf16* __restrict__ A) {
    const int tid = threadIdx.x;
    if (blockIdx.x < DEQ_BLOCKS) {
        int idx4 = blockIdx.x * 256 + tid;      // 0 .. 524287
        int n  = idx4 >> 7;                     // out row (128 chunks/row)
        int p4 = (idx4 & 127) << 2;             // first packed col (0..508)
        int g  = p4 >> 4;                       // group id (constant over 4)
        u32 qz = qzeros[(n << 2) + (g >> 3)];
        float z = (float)((qz >> ((g & 7) * 4)) & 15);
        float s = scales[(n << 5) + g];
        u32x4 qw = *(const u32x4*)(qweight + (size_t)n * 512 + p4);
        __bf16* dst = W + (size_t)n * IN_F + p4 * 8;
#pragma unroll
        for (int c = 0; c < 4; ++c) {
            bf16x8 h;
#pragma unroll
            for (int j = 0; j < 8; ++j) {
                float w = ((float)((qw[c] >> (4 * j)) & 15) - z) * s;
                h[j] = (__bf16)w;
            }
            *(bf16x8*)(dst + c * 8) = h;
        }
    } else {
        int idx = (blockIdx.x - DEQ_BLOCKS) * 256 + tid;   // 0 .. 1048575
        const f32x4* xp = (const f32x4*)x + (size_t)idx * 4;
        f32x4 v0 = xp[0], v1 = xp[1], v2 = xp[2], v3 = xp[3];
        bf16x8 h0, h1;
#pragma unroll
        for (int j = 0; j < 4; ++j) {
            h0[j] = (__bf16)v0[j]; h0[4 + j] = (__bf16)v1[j];
            h1[j] = (__bf16)v2[j]; h1[4 + j] = (__bf16)v3[j];
        }
        bf16x8* ap = (bf16x8*)A + (size_t)idx * 2;
        ap[0] = h0; ap[1] = h1;
    }
}

// ---------------------------------------------------------------------------
// GEMM: C[m][n] = sum_k A[m][k]*B[n][k] + bias[n]   (B^T-input form)
//    128x128 tile, BK=64 (32 MFMA per barrier-pair, halves barrier drains
//    vs BK=32), 256 threads (4 waves, 2x2 of 64x64), mfma 16x16x32_bf16
//    4x4 per wave, global_load_lds width=16 staging, LDS 32 KB total
//    (still 4 blocks/CU with __launch_bounds__(256,4)).
//    Swizzle: row = 8 chunks of 16B; LDS slot s of row r holds global
//    chunk s ^ (r&7) -> fragment ds_read_b128 (16 lanes, 128B row stride)
//    covers all 8 bank-quads per 8-lane phase; residual 2-way is free.
// ---------------------------------------------------------------------------
__global__ __launch_bounds__(256, 4) void gemm_bt(
        const __bf16* __restrict__ A, const __bf16* __restrict__ B,
        const float* __restrict__ bias, float* __restrict__ C) {
    __shared__ __align__(16) __bf16 lsA[128 * 64];
    __shared__ __align__(16) __bf16 lsB[128 * 64];

    const int t    = threadIdx.x;
    const int bm   = blockIdx.y, bn = blockIdx.x;
    const int lane = t & 63, wave = t >> 6;
    const int wm   = (wave >> 1) * 64;
    const int wn   = (wave & 1) * 64;
    const int lr   = lane & 15;
    const int quad = lane >> 4;

    const __bf16* Abase = A + (size_t)bm * 128 * IN_F;
    const __bf16* Bbase = B + (size_t)bn * 128 * IN_F;

    // staging: 128x64 tile = 1024 x 16B chunks; thread t does chunks
    // t+256*u (u=0..3). chunk q -> row q>>3, slot q&7; fetch global chunk
    // (q&7) ^ (row&7). LDS dest contiguous (q*16), as global_load_lds needs.
    int srow[4], scol[4];
#pragma unroll
    for (int u = 0; u < 4; ++u) {
        int q = t + u * 256;
        srow[u] = q >> 3;
        scol[u] = ((q & 7) ^ ((q >> 3) & 7)) * 8;
    }

    f32x4 acc[4][4] = {};

    for (int k0 = 0; k0 < IN_F; k0 += 64) {
#pragma unroll
        for (int u = 0; u < 4; ++u) {
            int q = t + u * 256;
            gld_lds16(Abase + (size_t)srow[u] * IN_F + k0 + scol[u],
                      (char*)lsA + q * 16);
            gld_lds16(Bbase + (size_t)srow[u] * IN_F + k0 + scol[u],
                      (char*)lsB + q * 16);
        }
        __syncthreads();

#pragma unroll
        for (int sub = 0; sub < 2; ++sub) {
            bf16x8 af[4], bf[4];
#pragma unroll
            for (int i = 0; i < 4; ++i) {
                const int Ra = wm + i * 16 + lr;
                const int Rb = wn + i * 16 + lr;
                const int ca = ((sub * 4 + quad) ^ (Ra & 7)) * 8;
                const int cb = ((sub * 4 + quad) ^ (Rb & 7)) * 8;
                af[i] = *(const bf16x8*)(lsA + Ra * 64 + ca);
                bf[i] = *(const bf16x8*)(lsB + Rb * 64 + cb);
            }
#pragma unroll
            for (int i = 0; i < 4; ++i)
#pragma unroll
                for (int j = 0; j < 4; ++j)
                    acc[i][j] = __builtin_amdgcn_mfma_f32_16x16x32_bf16(
                        af[i], bf[j], acc[i][j], 0, 0, 0);
        }
        __syncthreads();
    }

    // epilogue: C/D layout col = lane&15, row = (lane>>4)*4 + reg
    const int row0 = bm * 128 + wm + quad * 4;
    const int col0 = bn * 128 + wn + lr;
#pragma unroll
    for (int j = 0; j < 4; ++j) {
        const int col = col0 + j * 16;
        const float bv = bias[col];
#pragma unroll
        for (int i = 0; i < 4; ++i) {
            const int row = row0 + i * 16;
#pragma unroll
            for (int r = 0; r < 4; ++r)
                C[(size_t)(row + r) * OUT_F + col] = acc[i][j][r] + bv;
        }
    }
}

extern "C" void kernel_launch(void* const* d_in, const int* in_sizes, int n_in,
                              void* d_out, int out_size, void* d_ws, size_t ws_size,
                              hipStream_t stream) {
    (void)in_sizes; (void)n_in; (void)out_size; (void)ws_size;
    const float* x       = (const float*)d_in[0];
    const u32*   qweight = (const u32*)d_in[1];
    const u32*   qzeros  = (const u32*)d_in[2];
    const float* scales  = (const float*)d_in[3];
    const float* bias    = (const float*)d_in[4];
    float* out = (float*)d_out;

    __bf16* W   = (__bf16*)d_ws;                                     // 32 MB
    __bf16* Abf = (__bf16*)((char*)d_ws + (size_t)OUT_F * IN_F * 2); // 32 MB

    prep_kernel<<<dim3(DEQ_BLOCKS + CVT_BLOCKS), dim3(256), 0, stream>>>(
        qweight, qzeros, scales, x, W, Abf);
    gemm_bt<<<dim3(OUT_F / 128, TOKENS / 128), dim3(256), 0, stream>>>(
        Abf, W, bias, out);
}